// Round 1
// 48.183 us; speedup vs baseline: 1.0514x; 1.0514x over previous
//
#include <hip/hip_runtime.h>
#include <hip/hip_bf16.h>

#define HW 3136     // 56*56
#define CC 256
#define MM 72       // K*K*G (real)
#define HH 56
#define WW 56

typedef __attribute__((ext_vector_type(8))) short short8;   // 8 bf16 (4 VGPR)
typedef __attribute__((ext_vector_type(4))) float f32x4;    // MFMA acc / float4

__device__ inline unsigned short f2b(float f) {
    unsigned u; __builtin_memcpy(&u, &f, 4);
    unsigned r = u + 0x7fffu + ((u >> 16) & 1u);   // RNE to bf16
    return (unsigned short)(r >> 16);
}
__device__ inline float b2f(unsigned short s) {
    unsigned u = ((unsigned)s) << 16; float f; __builtin_memcpy(&f, &u, 4);
    return f;
}
__device__ __forceinline__ unsigned short f2b_native(float f) {
    __hip_bfloat16 h = __float2bfloat16(f);         // RNE; compiler can pack-cvt
    unsigned short s; __builtin_memcpy(&s, &h, 2);
    return s;
}

// fire-and-forget 16B global -> LDS DMA (no VGPR round-trip; counted in vmcnt)
__device__ __forceinline__ void gl2lds16(const float* g, float* l) {
    __builtin_amdgcn_global_load_lds(
        (const __attribute__((address_space(1))) void*)g,
        (__attribute__((address_space(3))) void*)l, 16, 0, 0);
}

// ---------------------------------------------------------------------------
// k0: fold the two 1x1 convs into bf16 W [80][256] (rows 72..95 zero) and
// fp32 bias [80]. (verified, unchanged)
// ---------------------------------------------------------------------------
__global__ __launch_bounds__(256) void k0_combine(
    const float* __restrict__ w_reduce,   // [128][256]
    const float* __restrict__ b_reduce,   // [128]
    const float* __restrict__ w_span,     // [72][128]
    const float* __restrict__ b_span,     // [72]
    unsigned short* __restrict__ wbf,     // [80][256] bf16
    float* __restrict__ bcomb)            // [80]
{
    __shared__ float red[4][64];
    __shared__ float redb[256];

    const int m  = blockIdx.x;       // 0..79
    const int cq = blockIdx.y;       // 0..3
    const int t  = threadIdx.x;
    const int oq = t >> 6;           // o-chunk (wave id)
    const int cl = t & 63;
    const int c  = cq * 64 + cl;

    float acc = 0.f;
    if (m < MM) {
        const float* wsB = w_span   + m * 128 + oq * 32;
        const float* wrB = w_reduce + (size_t)(oq * 32) * 256 + c;
#pragma unroll 8
        for (int o = 0; o < 32; ++o)
            acc = fmaf(wsB[o], wrB[(size_t)o * 256], acc);
    }
    if (oq != 0) red[oq][cl] = acc;
    __syncthreads();
    if (oq == 0)
        wbf[m * 256 + c] = f2b(acc + red[1][cl] + red[2][cl] + red[3][cl]);

    if (cq == 0) {   // uniform per block -> safe to sync inside
        redb[t] = (m < MM && t < 128) ? w_span[m * 128 + t] * b_reduce[t] : 0.f;
        __syncthreads();
#pragma unroll
        for (int s2 = 128; s2 > 0; s2 >>= 1) {
            if (t < s2) redb[t] += redb[t + s2];
            __syncthreads();
        }
        if (t == 0) bcomb[m] = (m < MM ? b_span[m] : 0.f) + redb[0];
    }
}

// ---------------------------------------------------------------------------
// k_fused: per (b, 4-row x 28-col tile) block:
//   phase A: ker[80][112] = W[80][256] @ x[256][112] + bias  (k1's MFMA
//            scheme: bit-swap-permuted LDS rows, 4 staged 64-ch chunks,
//            1792 quads = exactly 4 DMA/thread, 7 waves = 7 n-tiles)
//            -> ker parked in LDS as bf16 (never touches HBM)
//   phase B: 8 chunks of 32 ch (= one involution group each): stage haloed
//            x tile [32][6 rows][36 cols] (aligned clamped quads, k2's
//            mask trick: vm rows / lm / rm edge taps), apply 3x3, write out.
// x hits HBM exactly once (phase A); phase-B re-stage comes from L2/L3.
// grid(448 = 8*56 XCD-chunk swizzle), block(448). LDS 46.6 KB -> 2 blk/CU
// at <=128 VGPR -> all 448 blocks co-resident (no tail).
// ---------------------------------------------------------------------------
__global__ __launch_bounds__(448, 4) void k_fused(
    const float* __restrict__ x,              // [16][256][3136] fp32
    const unsigned short* __restrict__ wbf,   // [80][256] bf16
    const float* __restrict__ bcomb,          // [80]
    float* __restrict__ out)                  // [16][256][3136] fp32
{
    __shared__ float xsb[7168];               // 28672 B: A:[64][112] / B:[32][6][36]
    __shared__ unsigned short kl[80 * 112];   // 17920 B ker bf16

    const int L   = blockIdx.x;               // 0..447
    const int wk  = (L & 7) * 56 + (L >> 3);  // bijective (448 = 8*56)
    const int b   = wk / 28;
    const int rem = wk - b * 28;
    const int ht  = rem >> 1;                 // 0..13
    const int cs  = rem & 1;                  // column half
    const int h0  = ht * 4;
    const int c0  = cs * 28;

    const int t    = threadIdx.x;             // 0..447
    const int wv   = t >> 6;                  // wave 0..6 = GEMM n-tile
    const int lane = t & 63;
    const int l15  = lane & 15;
    const int q    = lane >> 4;

    // staging / apply decomposition: t = chh*28 + rA*7 + qA (rA<4, qA<7)
    const int chh   = t / 28;                 // 0..15
    const int rem28 = t - chh * 28;
    const int rA    = rem28 / 7;              // out row in band
    const int qA    = rem28 - rA * 7;         // 4-col strip
    // GEMM DMA: f = i*448+t -> rho = chh + 16*i (448/28=16 exact), c bit-swap
    const int cb  = ((chh & 7) << 3) | (chh >> 3);
    const int pxo = (h0 + rA) * WW + c0 + qA * 4;

    const float* xb = x + (size_t)b * CC * HW;

    // ---------------- phase A: GEMM ----------------
    f32x4 acc[5];
#pragma unroll
    for (int mt = 0; mt < 5; ++mt)
#pragma unroll
        for (int r = 0; r < 4; ++r)
            acc[mt][r] = bcomb[mt * 16 + q * 4 + r];

#pragma unroll 1
    for (int s = 0; s < 4; ++s) {
        if (s) __syncthreads();               // previous-stage reads done
#pragma unroll
        for (int i = 0; i < 4; ++i)           // rho = chh+16i -> c = cb+2i
            gl2lds16(xb + (size_t)(s * 64 + cb + 2 * i) * HW + pxo,
                     xsb + (i * 448 + t) * 4);
        __syncthreads();                      // drain DMA (vmcnt0 + barrier)
#pragma unroll
        for (int ks = 0; ks < 2; ++ks) {
            union { short8 v; unsigned short u16[8]; } bq;
#pragma unroll
            for (int j = 0; j < 8; ++j)       // row j*8+ks*4+q holds c=ks*32+q*8+j
                bq.u16[j] = f2b_native(xsb[(j * 8 + ks * 4 + q) * 112 + wv * 16 + l15]);
#pragma unroll
            for (int mt = 0; mt < 5; ++mt) {
                const short8 aq = *(const short8*)&wbf[(mt * 16 + l15) * 256 + s * 64 + ks * 32 + q * 8];
                acc[mt] = __builtin_amdgcn_mfma_f32_16x16x32_bf16(aq, bq.v, acc[mt], 0, 0, 0);
            }
        }
    }
    // ker -> LDS bf16 (rows 72..79 are zero-weight garbage, never read)
#pragma unroll
    for (int mt = 0; mt < 5; ++mt)
#pragma unroll
        for (int r = 0; r < 4; ++r)
            kl[(mt * 16 + q * 4 + r) * 112 + wv * 16 + l15] = f2b(acc[mt][r]);

    // ---------------- phase B: apply ----------------
    const int h = h0 + rA;

    float vm[3];
#pragma unroll
    for (int kh = 0; kh < 3; ++kh) {
        const int row = h - 1 + kh;
        vm[kh] = (row >= 0 && row < HH) ? 1.f : 0.f;
    }
    const float lm  = (cs == 0 && qA == 0) ? 0.f : 1.f;   // w-1 < 0
    const float rmm = (cs == 1 && qA == 6) ? 0.f : 1.f;   // w+4 > 55

    // per-i staging source offsets (g-invariant): 1728 = 32ch x 6rr x 9qd
    // i<3 full; i==3 active for waves 0..5 only (whole-wave uniform)
    int aoff[4];
#pragma unroll
    for (int i = 0; i < 4; ++i) {
        const int f = i * 448 + t;
        if (f < 1728) {
            const int d  = f / 54;            // ch in chunk 0..31
            const int r2 = f - d * 54;
            const int rr = r2 / 9;            // stage row 0..5 (h0-1..h0+4)
            const int qd = r2 - rr * 9;       // quad 0..8, holds w = c0-4+4qd..+3
            const int hh = h0 - 1 + rr;
            const int hc = hh < 0 ? 0 : (hh > 55 ? 55 : hh);
            int colc = c0 - 4 + qd * 4;       // 16B-aligned, clamped borders masked
            colc = colc < 0 ? 0 : (colc > 52 ? 52 : colc);
            aoff[i] = d * HW + hc * WW + colc;
        } else aoff[i] = -1;
    }

#pragma unroll 1
    for (int g = 0; g < 8; ++g) {             // chunk = group (C/G = 32 = chunk)
        __syncthreads();                      // prev-chunk reads / phase A done
#pragma unroll
        for (int i = 0; i < 4; ++i)
            if (aoff[i] >= 0)
                gl2lds16(xb + (size_t)g * 32 * HW + aoff[i],
                         xsb + (i * 448 + t) * 4);

        // ker taps from LDS while DMA in flight (kl region disjoint from xsb)
        ushort4 krb[9];
#pragma unroll
        for (int kk = 0; kk < 9; ++kk)
            krb[kk] = *(const ushort4*)&kl[(g * 9 + kk) * 112 + rA * 28 + qA * 4];

        __syncthreads();                      // drain DMA

        f32x4 kr[9];
#pragma unroll
        for (int kh = 0; kh < 3; ++kh) {
#pragma unroll
            for (int j = 0; j < 3; ++j) {
                const int kk = kh * 3 + j;
                kr[kk].x = b2f(krb[kk].x) * vm[kh];
                kr[kk].y = b2f(krb[kk].y) * vm[kh];
                kr[kk].z = b2f(krb[kk].z) * vm[kh];
                kr[kk].w = b2f(krb[kk].w) * vm[kh];
            }
            kr[kh * 3 + 0].x *= lm;           // tap reads col c0+4qA-1
            kr[kh * 3 + 2].w *= rmm;          // tap reads col c0+4qA+4
        }

        float* ob = out + ((size_t)b * CC + g * 32 + chh * 2) * HW + h * WW + c0 + qA * 4;
#pragma unroll
        for (int dd = 0; dd < 2; ++dd) {
            const float* bp = xsb + (chh * 2 + dd) * 216;   // ch stride 6*36
            f32x4 a = {0.f, 0.f, 0.f, 0.f};
#pragma unroll
            for (int kh = 0; kh < 3; ++kh) {
                const float* rowp = bp + (rA + kh) * 36;    // stage row rA+kh
                const f32x4 q0v = *(const f32x4*)(rowp + qA * 4);      // .w = w0-1
                const f32x4 q1v = *(const f32x4*)(rowp + qA * 4 + 4);  // w0..w0+3
                const float tl  = rowp[qA * 4 + 8];                    // w0+4
                const float w0 = q0v.w, w1 = q1v.x, w2 = q1v.y,
                            w3 = q1v.z, w4 = q1v.w, w5 = tl;
                const f32x4 k0v = kr[kh * 3 + 0];
                const f32x4 k1v = kr[kh * 3 + 1];
                const f32x4 k2v = kr[kh * 3 + 2];
                a.x = fmaf(k0v.x, w0, a.x); a.y = fmaf(k0v.y, w1, a.y);
                a.z = fmaf(k0v.z, w2, a.z); a.w = fmaf(k0v.w, w3, a.w);
                a.x = fmaf(k1v.x, w1, a.x); a.y = fmaf(k1v.y, w2, a.y);
                a.z = fmaf(k1v.z, w3, a.z); a.w = fmaf(k1v.w, w4, a.w);
                a.x = fmaf(k2v.x, w2, a.x); a.y = fmaf(k2v.y, w3, a.y);
                a.z = fmaf(k2v.z, w4, a.z); a.w = fmaf(k2v.w, w5, a.w);
            }
            *(f32x4*)(ob + (size_t)dd * HW) = a;
        }
    }
}

// ---------------------------------------------------------------------------
extern "C" void kernel_launch(void* const* d_in, const int* in_sizes, int n_in,
                              void* d_out, int out_size, void* d_ws, size_t ws_size,
                              hipStream_t stream) {
    const float* x        = (const float*)d_in[0];
    const float* w_reduce = (const float*)d_in[1];
    const float* b_reduce = (const float*)d_in[2];
    const float* w_span   = (const float*)d_in[3];
    const float* b_span   = (const float*)d_in[4];
    float* out = (float*)d_out;

    char* ws = (char*)d_ws;
    unsigned short* wbf   = (unsigned short*)ws;              // 40960 B
    float*          bcomb = (float*)(ws + 40960);             // 320 B

    k0_combine<<<dim3(80, 4), 256, 0, stream>>>(w_reduce, b_reduce, w_span, b_span,
                                                wbf, bcomb);
    k_fused<<<dim3(448), 448, 0, stream>>>(x, wbf, bcomb, out);
}

// Round 2
// 37.039 us; speedup vs baseline: 1.3677x; 1.3009x over previous
//
#include <hip/hip_runtime.h>
#include <hip/hip_bf16.h>

#define HW 3136     // 56*56
#define CC 256
#define MM 72       // K*K*G (real)
#define HH 56
#define WW 56

typedef __attribute__((ext_vector_type(8))) short short8;   // 8 bf16 (4 VGPR)
typedef __attribute__((ext_vector_type(4))) float f32x4;    // MFMA acc / float4

#define WAITVM(n) asm volatile("s_waitcnt vmcnt(" #n ")" ::: "memory")

__device__ __forceinline__ void blockbar() {
    asm volatile("" ::: "memory");        // compiler fence: nothing crosses
    __builtin_amdgcn_s_barrier();         // raw barrier: NO auto vmcnt(0) drain
    asm volatile("" ::: "memory");
}

__device__ inline unsigned short f2b(float f) {
    unsigned u; __builtin_memcpy(&u, &f, 4);
    unsigned r = u + 0x7fffu + ((u >> 16) & 1u);   // RNE to bf16
    return (unsigned short)(r >> 16);
}
__device__ inline float b2f(unsigned short s) {
    unsigned u = ((unsigned)s) << 16; float f; __builtin_memcpy(&f, &u, 4);
    return f;
}
__device__ __forceinline__ unsigned short f2b_native(float f) {
    __hip_bfloat16 h = __float2bfloat16(f);
    unsigned short s; __builtin_memcpy(&s, &h, 2);
    return s;
}

// fire-and-forget 16B global -> LDS DMA (counted in vmcnt; LDS dst MUST be
// wave-uniform base + lane*16 -> all dst index maps below are linear in t)
__device__ __forceinline__ void gl2lds16(const float* g, float* l) {
    __builtin_amdgcn_global_load_lds(
        (const __attribute__((address_space(1))) void*)g,
        (__attribute__((address_space(3))) void*)l, 16, 0, 0);
}

// ---------------------------------------------------------------------------
// k0: fold the two 1x1 convs into bf16 W [80][256] (rows 72..95 zero) and
// fp32 bias [80]. (verified, unchanged)
// ---------------------------------------------------------------------------
__global__ __launch_bounds__(256) void k0_combine(
    const float* __restrict__ w_reduce,   // [128][256]
    const float* __restrict__ b_reduce,   // [128]
    const float* __restrict__ w_span,     // [72][128]
    const float* __restrict__ b_span,     // [72]
    unsigned short* __restrict__ wbf,     // [80][256] bf16
    float* __restrict__ bcomb)            // [80]
{
    __shared__ float red[4][64];
    __shared__ float redb[256];

    const int m  = blockIdx.x;       // 0..79
    const int cq = blockIdx.y;       // 0..3
    const int t  = threadIdx.x;
    const int oq = t >> 6;           // o-chunk (wave id)
    const int cl = t & 63;
    const int c  = cq * 64 + cl;

    float acc = 0.f;
    if (m < MM) {
        const float* wsB = w_span   + m * 128 + oq * 32;
        const float* wrB = w_reduce + (size_t)(oq * 32) * 256 + c;
#pragma unroll 8
        for (int o = 0; o < 32; ++o)
            acc = fmaf(wsB[o], wrB[(size_t)o * 256], acc);
    }
    if (oq != 0) red[oq][cl] = acc;
    __syncthreads();
    if (oq == 0)
        wbf[m * 256 + c] = f2b(acc + red[1][cl] + red[2][cl] + red[3][cl]);

    if (cq == 0) {   // uniform per block -> safe to sync inside
        redb[t] = (m < MM && t < 128) ? w_span[m * 128 + t] * b_reduce[t] : 0.f;
        __syncthreads();
#pragma unroll
        for (int s2 = 128; s2 > 0; s2 >>= 1) {
            if (t < s2) redb[t] += redb[t + s2];
            __syncthreads();
        }
        if (t == 0) bcomb[m] = (m < MM ? b_span[m] : 0.f) + redb[0];
    }
}

// ---------------------------------------------------------------------------
// k_fused (pipelined): 16 phases = 8 GEMM stages (32 ch each) + 8 apply
// chunks (32 ch each), double-buffered LDS (parity stride 6912 floats),
// counted-vmcnt software pipeline (loads for phase k+2 issued after phase
// k's post-compute barrier; stores stay in flight across barriers).
//
// Per-wave vmcnt ledger (waves 0-4 / waves 5-6 issue 3 / 2 vm-ops per A-phase;
// every wave issues 4 loads + 2 stores per B-phase; wave 6's masked 4th
// B-load is replaced by a duplicate of its own i=2 chunk to keep counts
// uniform):
//   prologue: X(0),W(0),X(1),W(1)
//   A-phase s<7 : wait vmcnt(3) [w0-4] / vmcnt(2) [w5-6]  (newer = X,W of s+1)
//   A-phase s==7: wait vmcnt(4)                            (newer = B-G0 loads)
//   B-phase g==0: wait vmcnt(4)  (newer = G1 loads)
//   B-phase 1..6: wait vmcnt(6)  (newer = 2 stores(g-1) + 4 loads(g+1))
//   B-phase g==7: wait vmcnt(2)  (newer = 2 stores(g==6))
// No plain global loads inside the loops (wbf is DMA-staged to LDS; A-frag
// b128 reads use an XOR swizzle, conflict-free per quarter-wave; source is
// pre-swizzled so the DMA LDS dst stays linear).
// grid(448 = 8*56 XCD swizzle), block(448). LDS 81664 B -> 2 blk/CU.
// ---------------------------------------------------------------------------
__global__ __launch_bounds__(448, 4) void k_fused(
    const float* __restrict__ x,              // [16][256][3136] fp32
    const unsigned short* __restrict__ wbf,   // [80][256] bf16
    const float* __restrict__ bcomb,          // [80]
    float* __restrict__ out)                  // [16][256][3136] fp32
{
    __shared__ __align__(16) float xsb[13824];            // 2 x 6912 f (55296 B)
    __shared__ __align__(16) unsigned short wsl[2][2560]; // 2 x 80x32 bf16 (10240 B)
    __shared__ __align__(16) unsigned short kl[MM * 112]; // 16128 B  (total 81664 B)

    const int L   = blockIdx.x;               // 0..447
    const int wk  = (L & 7) * 56 + (L >> 3);  // bijective (448 = 8*56)
    const int b   = wk / 28;
    const int rem = wk - b * 28;
    const int ht  = rem >> 1;                 // 0..13
    const int cs  = rem & 1;                  // column half
    const int h0  = ht * 4;
    const int c0  = cs * 28;

    const int t    = threadIdx.x;             // 0..447
    const int lane = t & 63;
    const int wv   = t >> 6;                  // wave 0..6 = GEMM n-tile
    const int l15  = lane & 15;
    const int q    = lane >> 4;

    const int chh   = t / 28;                 // 0..15
    const int rem28 = t - chh * 28;
    const int rA    = rem28 / 7;              // out row in band
    const int qA    = rem28 - rA * 7;         // 4-col strip

    const float* xb = x + (size_t)b * CC * HW;

    // ---- per-thread constants ----
    const int nb   = wv * 16 + l15;                // GEMM n = tile px (row-major 4x28)
    const int nb2  = q * 112 + nb;                 // B-frag base (j stride 448)
    const int swA  = (l15 ^ (l15 >> 2)) & 3;       // A-frag XOR swizzle
    const int aBo  = l15 * 32 + (q ^ swA) * 8;     // A-frag base (mt stride 512)
    const int cA   = ((chh & 3) << 3) | (chh >> 2);// x-DMA channel perm (i adds +4)
    const int pxo  = (h0 + rA) * WW + c0 + qA * 4; // x-DMA pixel offset
    // wbf-DMA pre-swizzled source (dst stays linear = t*16B, t<320 only)
    const int wswr = ((t >> 2) ^ (t >> 4)) & 3;
    const unsigned short* wsrc0 = wbf + (t >> 2) * 256 + ((t & 3) ^ wswr) * 8;

    // ---- B-phase staging descriptors (g-invariant) ----
    int aoffv[4], bdst[4];
#pragma unroll
    for (int i = 0; i < 4; ++i) {
        int f = i * 448 + t;
        if (f >= 1728) f -= 448;          // wave-6 dup of its own i=2 chunk
        const int d  = f / 54;            // ch in chunk 0..31
        const int r2 = f - d * 54;
        const int rr = r2 / 9;            // stage row 0..5 (h0-1..h0+4)
        const int qd = r2 - rr * 9;       // quad 0..8
        const int hh = h0 - 1 + rr;
        const int hc = hh < 0 ? 0 : (hh > 55 ? 55 : hh);
        int colc = c0 - 4 + qd * 4;       // 16B-aligned; clamped borders masked
        colc = colc < 0 ? 0 : (colc > 52 ? 52 : colc);
        aoffv[i] = d * HW + hc * WW + colc;
        bdst[i]  = f * 4;                 // linear: base + lane*16B per wave
    }

    // ---- apply masks (g-invariant) ----
    float vmm[3];
#pragma unroll
    for (int kh = 0; kh < 3; ++kh) {
        const int row = h0 + rA - 1 + kh;
        vmm[kh] = (row >= 0 && row < HH) ? 1.f : 0.f;
    }
    const float lm  = (cs == 0 && qA == 0) ? 0.f : 1.f;   // w-1 < 0
    const float rmm = (cs == 1 && qA == 6) ? 0.f : 1.f;   // w+4 > 55

    // ---- stage helpers (all LDS dst linear in t) ----
    auto stageX = [&](int s, int p) {     // 2 x-chunk DMA (rows chh, chh+16)
        const float* sp = xb + (size_t)(s * 32 + cA) * HW + pxo;
        float* dp = xsb + p * 6912 + t * 4;
        gl2lds16(sp, dp);
        gl2lds16(sp + (size_t)4 * HW, dp + 1792);
    };
    auto stageW = [&](int s, int p) {     // 1 wbf-slice DMA (waves 0-4 only)
        if (t < 320)
            gl2lds16((const float*)(wsrc0 + s * 32), (float*)(wsl[p]) + t * 4);
    };
    auto stageB = [&](int g, int p) {     // 4 halo-chunk DMA (wave-6 i=3 dup)
        const float* gp = xb + (size_t)g * 32 * HW;
        float* dp = xsb + p * 6912;
#pragma unroll
        for (int i = 0; i < 4; ++i)
            gl2lds16(gp + aoffv[i], dp + bdst[i]);
    };

    // ---- acc init (plain loads; older than all DMA -> drained by first wait)
    f32x4 acc[5];
#pragma unroll
    for (int mt = 0; mt < 5; ++mt)
#pragma unroll
        for (int r = 0; r < 4; ++r)
            acc[mt][r] = bcomb[mt * 16 + q * 4 + r];

    // ---- prologue ----
    stageX(0, 0); stageW(0, 0);
    stageX(1, 1); stageW(1, 1);

    // ---------------- phase A: 8 pipelined GEMM stages ----------------
#pragma unroll 1
    for (int s = 0; s < 8; ++s) {
        const int p = s & 1;
        if (s < 7) { if (t < 320) WAITVM(3); else WAITVM(2); }
        else       { WAITVM(4); }
        blockbar();

        const float* bufA = xsb + p * 6912;
        const unsigned short* wp = wsl[p];
        union { short8 v; unsigned short u16[8]; } bq;
#pragma unroll
        for (int j = 0; j < 8; ++j)       // row j*4+q holds channel q*8+j
            bq.u16[j] = f2b_native(bufA[nb2 + j * 448]);
#pragma unroll
        for (int mt = 0; mt < 5; ++mt) {
            const short8 aq = *(const short8*)&wp[mt * 512 + aBo];
            acc[mt] = __builtin_amdgcn_mfma_f32_16x16x32_bf16(aq, bq.v, acc[mt], 0, 0, 0);
        }
        if (s == 7) {                     // ker -> LDS bf16 (rows 72..79 dropped)
#pragma unroll
            for (int mt = 0; mt < 5; ++mt)
#pragma unroll
                for (int r = 0; r < 4; ++r) {
                    const int m = mt * 16 + q * 4 + r;
                    if (m < MM) kl[m * 112 + nb] = f2b(acc[mt][r]);
                }
            asm volatile("s_waitcnt lgkmcnt(0)" ::: "memory");
        }
        blockbar();
        if (s < 6) { stageX(s + 2, p); stageW(s + 2, p); }
        else       { stageB(s - 6, p); }   // s==6 -> G0 (parity 0), s==7 -> G1
    }

    // ---------------- phase B: 8 pipelined apply chunks ----------------
#pragma unroll 1
    for (int g = 0; g < 8; ++g) {
        const int p = g & 1;
        if (g == 0)      WAITVM(4);
        else if (g == 7) WAITVM(2);
        else             WAITVM(6);
        blockbar();

        ushort4 krb[9];
#pragma unroll
        for (int kk = 0; kk < 9; ++kk)
            krb[kk] = *(const ushort4*)&kl[(g * 9 + kk) * 112 + rA * 28 + qA * 4];

        f32x4 kr[9];
#pragma unroll
        for (int kh = 0; kh < 3; ++kh) {
#pragma unroll
            for (int j = 0; j < 3; ++j) {
                const int kk = kh * 3 + j;
                kr[kk].x = b2f(krb[kk].x) * vmm[kh];
                kr[kk].y = b2f(krb[kk].y) * vmm[kh];
                kr[kk].z = b2f(krb[kk].z) * vmm[kh];
                kr[kk].w = b2f(krb[kk].w) * vmm[kh];
            }
            kr[kh * 3 + 0].x *= lm;       // tap reads col c0+4qA-1
            kr[kh * 3 + 2].w *= rmm;      // tap reads col c0+4qA+4
        }

        const float* bp0 = xsb + p * 6912;
        float* ob = out + ((size_t)b * CC + g * 32 + chh * 2) * HW
                  + (h0 + rA) * WW + c0 + qA * 4;
#pragma unroll
        for (int dd = 0; dd < 2; ++dd) {
            const float* bp = bp0 + (chh * 2 + dd) * 216;   // ch stride 6*36
            f32x4 a = {0.f, 0.f, 0.f, 0.f};
#pragma unroll
            for (int kh = 0; kh < 3; ++kh) {
                const float* rowp = bp + (rA + kh) * 36;
                const f32x4 q0v = *(const f32x4*)(rowp + qA * 4);      // .w = w0-1
                const f32x4 q1v = *(const f32x4*)(rowp + qA * 4 + 4);  // w0..w0+3
                const float tl  = rowp[qA * 4 + 8];                    // w0+4
                const float w0 = q0v.w, w1 = q1v.x, w2 = q1v.y,
                            w3 = q1v.z, w4 = q1v.w, w5 = tl;
                const f32x4 k0v = kr[kh * 3 + 0];
                const f32x4 k1v = kr[kh * 3 + 1];
                const f32x4 k2v = kr[kh * 3 + 2];
                a.x = fmaf(k0v.x, w0, a.x); a.y = fmaf(k0v.y, w1, a.y);
                a.z = fmaf(k0v.z, w2, a.z); a.w = fmaf(k0v.w, w3, a.w);
                a.x = fmaf(k1v.x, w1, a.x); a.y = fmaf(k1v.y, w2, a.y);
                a.z = fmaf(k1v.z, w3, a.z); a.w = fmaf(k1v.w, w4, a.w);
                a.x = fmaf(k2v.x, w2, a.x); a.y = fmaf(k2v.y, w3, a.y);
                a.z = fmaf(k2v.z, w4, a.z); a.w = fmaf(k2v.w, w5, a.w);
            }
            *(f32x4*)(ob + (size_t)dd * HW) = a;              // 2 stores/B-phase
        }

        blockbar();
        if (g < 6) stageB(g + 2, p);
    }
}

// ---------------------------------------------------------------------------
extern "C" void kernel_launch(void* const* d_in, const int* in_sizes, int n_in,
                              void* d_out, int out_size, void* d_ws, size_t ws_size,
                              hipStream_t stream) {
    const float* x        = (const float*)d_in[0];
    const float* w_reduce = (const float*)d_in[1];
    const float* b_reduce = (const float*)d_in[2];
    const float* w_span   = (const float*)d_in[3];
    const float* b_span   = (const float*)d_in[4];
    float* out = (float*)d_out;

    char* ws = (char*)d_ws;
    unsigned short* wbf   = (unsigned short*)ws;              // 40960 B
    float*          bcomb = (float*)(ws + 40960);             // 320 B

    k0_combine<<<dim3(80, 4), 256, 0, stream>>>(w_reduce, b_reduce, w_span, b_span,
                                                wbf, bcomb);
    k_fused<<<dim3(448), 448, 0, stream>>>(x, wbf, bcomb, out);
}